// Round 23
// baseline (44.872 us; speedup 1.0000x reference)
//
#include <hip/hip_runtime.h>
#include <math.h>

#ifndef M_PI
#define M_PI 3.14159265358979323846
#endif

namespace {
constexpr int kNSamples = 524288;
constexpr int kNGrains  = 4096;
constexpr int kGrainN   = 16384;
constexpr int kTile     = 512;                  // 2 adjacent samples/thread
constexpr int kNTiles   = kNSamples / kTile;    // 1024 tiles
constexpr int kGuard    = 1024;                 // guard entries each side ({0,0})
constexpr int kTabN     = kGrainN + 2 * kGuard; // 18432
constexpr int kChunk    = 256;                  // LDS grain-stage chunk
constexpr int kSortBlocks = 256;                // 16 grains/block, 16-way chunks

// ws layout (bytes), 16-aligned
constexpr size_t PART_OFF = 0;                        // double[512]        4 KB
constexpr size_t ONS_OFF  = PART_OFF + 8 * 512;       // int[kNGrains]     16 KB
constexpr size_t FC_OFF   = ONS_OFF + 4 * kNGrains;   // float2[kNGrains]  32 KB
constexpr size_t TAB_OFF  = FC_OFF + 8 * kNGrains;    // float2[kTabN]    144 KB
constexpr size_t OUT2_OFF = TAB_OFF + 8 * kTabN;      // float[kNSamples]   2 MB
constexpr size_t OUT3_OFF = OUT2_OFF + 4 * (size_t)kNSamples;
constexpr size_t OUT4_OFF = OUT3_OFF + 4 * (size_t)kNSamples;
constexpr size_t kWsNeedSplit = OUT4_OFF + 4 * (size_t)kNSamples;  // ~6.4 MB
}  // namespace

// Setup: blocks [0,256) rank-sort + coefs (16 grains/block, 16 key-chunks of
// 256); blocks [256,328) table {phase, w2} with {0,0} guards.
// rank[g] = #{h : (onset[h],h) < (onset[g],g)} -- deterministic, no atomics.
// max(amps) == amps[0] (amps strictly decreasing in g).
__global__ __launch_bounds__(256) void k_setup(const float* __restrict__ dens_p,
                                               const float* __restrict__ slope_p,
                                               const float* __restrict__ f0,
                                               const int* __restrict__ onsets,
                                               void* wsv) {
  char* ws = (char*)wsv;
  const int tid = threadIdx.x;

  if (blockIdx.x >= kSortBlocks) {
    const int e = (blockIdx.x - kSortBlocks) * 256 + tid;
    const int l = e - kGuard;
    float2 v = make_float2(0.0f, 0.0f);
    if ((unsigned)l < (unsigned)kGrainN) {
      const double ts    = (double)slope_p[0];
      const double gamma = tan(ts * M_PI / 2.0) * (44100.0 / (12.0 * 256.0)) / 4.0;
      const float  tf    = (float)l / 44100.0f - 0.18575963718820862f;  // ref f32 t
      const double ph = (gamma == 0.0) ? (double)tf
                                       : expm1(gamma * (double)tf) / gamma;
      const double wv = sin(M_PI * ((double)l / 16384.0));
      v = make_float2((float)ph, (float)(wv * wv));
    }
    ((float2*)(ws + TAB_OFF))[e] = v;
    return;
  }

  __shared__ int sons[kNGrains];        // 16 KB
  __shared__ int srank[16][17];         // padded

  for (int i = tid; i < kNGrains; i += 256) sons[i] = onsets[i];
  __syncthreads();

  const int gi = tid & 15;              // 16 grains per block
  const int g  = blockIdx.x * 16 + gi;
  const int ck = tid >> 4;              // 0..15 key-chunks of 256
  const int og = sons[g];

  int pr = 0;
  const int h0 = ck * 256;
#pragma unroll 8
  for (int h = h0; h < h0 + 256; ++h) {
    const int oh = sons[h];
    pr += (int)(oh < og) | ((int)(oh == og) & (int)(h < g));
  }
  srank[gi][ck] = pr;
  __syncthreads();

  if (tid < 16) {
    const int gg = blockIdx.x * 16 + tid;
    int rank = 0;
#pragma unroll
    for (int c = 0; c < 16; ++c) rank += srank[tid][c];

    const double d    = (double)dens_p[0];
    const double off  = 0.25 * d + 0.75 * d * d;
    const double c2   = 2.0 * (1.0 - d) * 4096.0;
    const double amp  = 1.0 / (1.0 + exp(c2 * ((double)gg / 4096.0 - off)));
    const double amp0 = 1.0 / (1.0 + exp(c2 * (0.0 - off)));  // max amp

    const float f0g = f0[gg];
    const float cg  = (float)(amp / amp0) / sqrtf(f0g);
    ((int*)(ws + ONS_OFF))[rank]    = sons[gg];
    ((float2*)(ws + FC_OFF))[rank]  = make_float2(f0g, cg);
  }
}

// Main (r14/r22 inner loop verbatim): 2 ADJACENT samples/thread, SPLIT blocks
// per tile. SPLIT=4 -> grid 4096 = 2 scheduling rounds of 2048: early-finishing
// CUs backfill with round-2 blocks, averaging out the per-tile grain-count
// imbalance (binomial mean 132, sigma~11) that made grid==capacity wait on
// the slowest block. Table loads per-lane VGPR addresses; onsets/fc as DATA
// via LDS group reads (depth-4 queues, unroll 4 renames). Pads: c=0
// annihilates; guard w2=0 kills OOB evals.
template <int SPLIT>
__global__ __launch_bounds__(256, 8) void k_main(const int* __restrict__ ONS,
                                                 const float2* __restrict__ FC,
                                                 const float2* __restrict__ TAB2,
                                                 float* __restrict__ o0,
                                                 float* __restrict__ o1,
                                                 float* __restrict__ o2,
                                                 float* __restrict__ o3) {
  __shared__ int    s_on[kChunk + 16];   // SoA, 16-pad for group reads
  __shared__ float2 s_fc[kChunk + 16];

  const int bid  = blockIdx.x;
  const int tile = bid / SPLIT;
  const int part = bid % SPLIT;
  const int tid  = threadIdx.x;
  const int s    = tile * kTile;
  float* __restrict__ dst = (part == 0) ? o0 : (part == 1) ? o1
                           : (part == 2) ? o2 : o3;

  // two independent binary searches (loads interleave)
  int lo, hi;
  {
    int a = 0, b = kNGrains, a2 = 0, b2 = kNGrains;
    const int t1 = s - kGrainN;
    const int t2 = s + kTile - 1;
    while (a < b || a2 < b2) {
      if (a < b)   { int m = (a + b) >> 1;   if (ONS[m] > t1) b = m;  else a = m + 1; }
      if (a2 < b2) { int m = (a2 + b2) >> 1; if (ONS[m] > t2) b2 = m; else a2 = m + 1; }
    }
    lo = a; hi = a2;
  }
  lo = __builtin_amdgcn_readfirstlane(lo);
  hi = __builtin_amdgcn_readfirstlane(hi);

  // this block's slice of the grain range
  const int n_all = hi - lo;
  const int gb = lo + (n_all * part) / SPLIT;
  const int ge = lo + (n_all * (part + 1)) / SPLIT;

  const int p0 = s + 2 * tid;                 // samples p0, p0+1
  const float2* TG2 = TAB2 + kGuard;          // entry l at TG2[l]
  float acc0 = 0.0f, acc1 = 0.0f;

  for (int base = gb; base < ge; base += kChunk) {
    const int n  = min(kChunk, ge - base);    // uniform
    const int n4 = (n + 3) & ~3;              // padded group count
    __syncthreads();
    for (int i = tid; i < n4 + 16; i += 256) {
      const int idx = min(base + i, ge - 1);
      s_on[i] = ONS[max(idx, 0)];
      s_fc[i] = (base + i < ge) ? FC[idx]
                                : make_float2(1.0f, 0.0f);  // pad: c=0 kills it
    }
    __syncthreads();

    const int4*   On4 = (const int4*)s_on;    // 4 grains per entry
    const float4* Fc4 = (const float4*)s_fc;  // 2 grains per entry

    // prologue: u queue = table values for grains 0..3 (addresses from On4[0]);
    // onQ = onsets 4..7; fc cur = grains 0..3.
    const int4 on0 = On4[0];
    float2 u0a = TG2[p0 - on0.x], u0b = TG2[p0 + 1 - on0.x];
    float2 u1a = TG2[p0 - on0.y], u1b = TG2[p0 + 1 - on0.y];
    float2 u2a = TG2[p0 - on0.z], u2b = TG2[p0 + 1 - on0.z];
    float2 u3a = TG2[p0 - on0.w], u3b = TG2[p0 + 1 - on0.w];
    int4   onQ = On4[1];
    float4 fcA = Fc4[0], fcB = Fc4[1];

    for (int t = 0; t < n4; t += 4) {
      // group-top reads (consumed next group: distance 4..7 iters)
      const int4   onI = On4[(t >> 2) + 2];          // onsets t+8..t+11
      const float4 fcI = Fc4[((t >> 2) + 1) * 2];    // fc t+4..t+5
      const float4 fcJ = Fc4[((t >> 2) + 1) * 2 + 1];// fc t+6..t+7

#pragma unroll
      for (int k = 0; k < 4; ++k) {
        // issue table loads for grain t+k+4 (per-lane VGPR address)
        const int onn = (k == 0) ? onQ.x : (k == 1) ? onQ.y
                       : (k == 2) ? onQ.z : onQ.w;
        const float2 na = TG2[p0 - onn];
        const float2 nb = TG2[p0 + 1 - onn];

        // compute grain t+k (u values loaded 4 iters ago)
        const float f0v = (k == 0) ? fcA.x : (k == 1) ? fcA.z
                         : (k == 2) ? fcB.x : fcB.z;
        const float cv  = (k == 0) ? fcA.y : (k == 1) ? fcA.w
                         : (k == 2) ? fcB.y : fcB.w;
        acc0 = fmaf(cv * u0a.y,
                    __builtin_amdgcn_sinf(__builtin_amdgcn_fractf(f0v * u0a.x)), acc0);
        acc1 = fmaf(cv * u0b.y,
                    __builtin_amdgcn_sinf(__builtin_amdgcn_fractf(f0v * u0b.x)), acc1);

        // rotate u queue (period 4 == unroll -> pure renaming)
        u0a = u1a; u0b = u1b; u1a = u2a; u1b = u2b;
        u2a = u3a; u2b = u3b; u3a = na;  u3b = nb;
      }
      onQ = onI; fcA = fcI; fcB = fcJ;
    }
  }

  // adjacent-sample float2 store (8B aligned: p0 even)
  *reinterpret_cast<float2*>(dst + p0) = make_float2(acc0, acc1);
}

// Combine NB buffers and compute per-block sum of squares (f64).
template <int NB>
__global__ __launch_bounds__(256) void k_norm(float4* __restrict__ A,
                                              const float4* __restrict__ B,
                                              const float4* __restrict__ C,
                                              const float4* __restrict__ D,
                                              double* __restrict__ partials) {
  __shared__ double wpart[4];
  const int tid = threadIdx.x;
  const int i   = blockIdx.x * 256 + tid;
  float4 v = A[i];
  if (NB >= 2) {
    const float4 w = B[i];
    v.x += w.x; v.y += w.y; v.z += w.z; v.w += w.w;
  }
  if (NB >= 3) {
    const float4 w = C[i];
    v.x += w.x; v.y += w.y; v.z += w.z; v.w += w.w;
  }
  if (NB >= 4) {
    const float4 w = D[i];
    v.x += w.x; v.y += w.y; v.z += w.z; v.w += w.w;
  }
  if (NB >= 2) A[i] = v;
  double p2 = (double)v.x * v.x + (double)v.y * v.y +
              (double)v.z * v.z + (double)v.w * v.w;
  for (int o = 32; o > 0; o >>= 1) p2 += __shfl_down(p2, o);
  if ((tid & 63) == 0) wpart[tid >> 6] = p2;
  __syncthreads();
  if (tid == 0) partials[blockIdx.x] = wpart[0] + wpart[1] + wpart[2] + wpart[3];
}

// Every block reduces the same 512 partials in the same order (deterministic,
// identical result), then scales its 1024-sample chunk by 1/sqrt(sum).
__global__ __launch_bounds__(256) void k_scale(const double* __restrict__ partials,
                                               float4* __restrict__ out) {
  __shared__ double red[256];
  const int tid = threadIdx.x;
  red[tid] = partials[tid] + partials[tid + 256];
  __syncthreads();
  for (int st = 128; st > 0; st >>= 1) {
    if (tid < st) red[tid] += red[tid + st];
    __syncthreads();
  }
  const float sc = (float)(1.0 / sqrt(red[0]));
  const int i = blockIdx.x * 256 + tid;
  float4 v = out[i];
  v.x *= sc; v.y *= sc; v.z *= sc; v.w *= sc;
  out[i] = v;
}

extern "C" void kernel_launch(void* const* d_in, const int* in_sizes, int n_in,
                              void* d_out, int out_size, void* d_ws, size_t ws_size,
                              hipStream_t stream) {
  const float* dens   = (const float*)d_in[0];
  const float* slope  = (const float*)d_in[1];
  const float* f0     = (const float*)d_in[2];
  const int*   onsets = (const int*)d_in[3];
  float* out = (float*)d_out;
  char*  ws  = (char*)d_ws;

  const int*    ONS  = (const int*)(ws + ONS_OFF);
  const float2* FC   = (const float2*)(ws + FC_OFF);
  const float2* TAB2 = (const float2*)(ws + TAB_OFF);
  double*       PART = (double*)(ws + PART_OFF);
  float*        o2   = (float*)(ws + OUT2_OFF);
  float*        o3   = (float*)(ws + OUT3_OFF);
  float*        o4   = (float*)(ws + OUT4_OFF);

  hipLaunchKernelGGL(k_setup, dim3(kSortBlocks + kTabN / 256), dim3(256), 0, stream,
                     dens, slope, f0, onsets, d_ws);

  if (ws_size >= kWsNeedSplit) {
    hipLaunchKernelGGL(k_main<4>, dim3(kNTiles * 4), dim3(256), 0, stream,
                       ONS, FC, TAB2, out, o2, o3, o4);
    hipLaunchKernelGGL(k_norm<4>, dim3(kNSamples / 1024), dim3(256), 0, stream,
                       (float4*)out, (const float4*)o2, (const float4*)o3,
                       (const float4*)o4, PART);
  } else {
    hipLaunchKernelGGL(k_main<1>, dim3(kNTiles), dim3(256), 0, stream,
                       ONS, FC, TAB2, out, out, out, out);
    hipLaunchKernelGGL(k_norm<1>, dim3(kNSamples / 1024), dim3(256), 0, stream,
                       (float4*)out, (const float4*)nullptr, (const float4*)nullptr,
                       (const float4*)nullptr, PART);
  }
  hipLaunchKernelGGL(k_scale, dim3(kNSamples / 1024), dim3(256), 0, stream,
                     PART, (float4*)out);
}

// Round 24
// 42.644 us; speedup vs baseline: 1.0523x; 1.0523x over previous
//
#include <hip/hip_runtime.h>
#include <math.h>

#ifndef M_PI
#define M_PI 3.14159265358979323846
#endif

namespace {
constexpr int kNSamples = 524288;
constexpr int kNGrains  = 4096;
constexpr int kGrainN   = 16384;
constexpr int kTile     = 512;                  // 2 adjacent samples/thread
constexpr int kNTiles   = kNSamples / kTile;    // 1024 tiles
constexpr int kGuard    = 1024;                 // guard entries each side ({0,0})
constexpr int kTabN     = kGrainN + 2 * kGuard; // 18432
constexpr int kChunk    = 256;                  // LDS grain-stage chunk
constexpr int kSortBlocks = 256;                // 16 grains/block, 16-way chunks

// ws layout (bytes), 16-aligned
constexpr size_t PART_OFF = 0;                        // double[512]        4 KB
constexpr size_t ONS_OFF  = PART_OFF + 8 * 512;       // int[kNGrains]     16 KB
constexpr size_t FC_OFF   = ONS_OFF + 4 * kNGrains;   // float2[kNGrains]  32 KB
constexpr size_t TAB_OFF  = FC_OFF + 8 * kNGrains;    // float2[kTabN]    144 KB
constexpr size_t OUT2_OFF = TAB_OFF + 8 * kTabN;      // float[kNSamples]   2 MB
constexpr size_t kWsNeedSplit = OUT2_OFF + 4 * (size_t)kNSamples;  // ~2.3 MB
}  // namespace

// Setup: blocks [0,256) rank-sort + coefs (16 grains/block, 16 key-chunks of
// 256 -> 256 compare-iters/thread); blocks [256,328) table {phase, w2} with
// {0,0} guards.
// rank[g] = #{h : (onset[h],h) < (onset[g],g)} -- deterministic, no atomics.
// max(amps) == amps[0] (amps strictly decreasing in g).
__global__ __launch_bounds__(256) void k_setup(const float* __restrict__ dens_p,
                                               const float* __restrict__ slope_p,
                                               const float* __restrict__ f0,
                                               const int* __restrict__ onsets,
                                               void* wsv) {
  char* ws = (char*)wsv;
  const int tid = threadIdx.x;

  if (blockIdx.x >= kSortBlocks) {
    const int e = (blockIdx.x - kSortBlocks) * 256 + tid;
    const int l = e - kGuard;
    float2 v = make_float2(0.0f, 0.0f);
    if ((unsigned)l < (unsigned)kGrainN) {
      const double ts    = (double)slope_p[0];
      const double gamma = tan(ts * M_PI / 2.0) * (44100.0 / (12.0 * 256.0)) / 4.0;
      const float  tf    = (float)l / 44100.0f - 0.18575963718820862f;  // ref f32 t
      const double ph = (gamma == 0.0) ? (double)tf
                                       : expm1(gamma * (double)tf) / gamma;
      const double wv = sin(M_PI * ((double)l / 16384.0));
      v = make_float2((float)ph, (float)(wv * wv));
    }
    ((float2*)(ws + TAB_OFF))[e] = v;
    return;
  }

  __shared__ int sons[kNGrains];        // 16 KB
  __shared__ int srank[16][17];         // padded

  for (int i = tid; i < kNGrains; i += 256) sons[i] = onsets[i];
  __syncthreads();

  const int gi = tid & 15;              // 16 grains per block
  const int g  = blockIdx.x * 16 + gi;
  const int ck = tid >> 4;              // 0..15 key-chunks of 256
  const int og = sons[g];

  int pr = 0;
  const int h0 = ck * 256;
#pragma unroll 8
  for (int h = h0; h < h0 + 256; ++h) {
    const int oh = sons[h];
    pr += (int)(oh < og) | ((int)(oh == og) & (int)(h < g));
  }
  srank[gi][ck] = pr;
  __syncthreads();

  if (tid < 16) {
    const int gg = blockIdx.x * 16 + tid;
    int rank = 0;
#pragma unroll
    for (int c = 0; c < 16; ++c) rank += srank[tid][c];

    const double d    = (double)dens_p[0];
    const double off  = 0.25 * d + 0.75 * d * d;
    const double c2   = 2.0 * (1.0 - d) * 4096.0;
    const double amp  = 1.0 / (1.0 + exp(c2 * ((double)gg / 4096.0 - off)));
    const double amp0 = 1.0 / (1.0 + exp(c2 * (0.0 - off)));  // max amp

    const float f0g = f0[gg];
    const float cg  = (float)(amp / amp0) / sqrtf(f0g);
    ((int*)(ws + ONS_OFF))[rank]    = sons[gg];
    ((float2*)(ws + FC_OFF))[rank]  = make_float2(f0g, cg);
  }
}

// Main (round-14 inner loop, best measured): 2 ADJACENT samples per thread,
// SPLIT blocks per tile (8 blocks/CU = 32 waves/CU at SPLIT=2).
// NO uniform-address chain: table loads use per-lane VGPR addresses
// (TG2 + (p0 - on)); onsets arrive as DATA via one ds_read_b128 per 4 grains
// (read 4..7 iters before use), fc via two ds_read_b128 per 4 grains. All
// waits are counted lgkmcnt/vmcnt on in-order queues. Groups padded to 4
// with c=0 (annihilates); guard w2=0 kills OOB evals.
template <int SPLIT>
__global__ __launch_bounds__(256, 8) void k_main(const int* __restrict__ ONS,
                                                 const float2* __restrict__ FC,
                                                 const float2* __restrict__ TAB2,
                                                 float* __restrict__ out0,
                                                 float* __restrict__ out1) {
  __shared__ int    s_on[kChunk + 16];   // SoA, 16-pad for group reads
  __shared__ float2 s_fc[kChunk + 16];

  const int bid  = blockIdx.x;
  const int tile = bid / SPLIT;
  const int half = bid % SPLIT;
  const int tid  = threadIdx.x;
  const int s    = tile * kTile;
  float* __restrict__ dst = (SPLIT == 2 && half == 1) ? out1 : out0;

  // two independent binary searches (loads interleave)
  int lo, hi;
  {
    int a = 0, b = kNGrains, a2 = 0, b2 = kNGrains;
    const int t1 = s - kGrainN;
    const int t2 = s + kTile - 1;
    while (a < b || a2 < b2) {
      if (a < b)   { int m = (a + b) >> 1;   if (ONS[m] > t1) b = m;  else a = m + 1; }
      if (a2 < b2) { int m = (a2 + b2) >> 1; if (ONS[m] > t2) b2 = m; else a2 = m + 1; }
    }
    lo = a; hi = a2;
  }
  lo = __builtin_amdgcn_readfirstlane(lo);
  hi = __builtin_amdgcn_readfirstlane(hi);

  // this block's slice of the grain range
  const int n_all = hi - lo;
  const int gb = lo + (n_all * half) / SPLIT;
  const int ge = lo + (n_all * (half + 1)) / SPLIT;

  const int p0 = s + 2 * tid;                 // samples p0, p0+1
  const float2* TG2 = TAB2 + kGuard;          // entry l at TG2[l]
  float acc0 = 0.0f, acc1 = 0.0f;

  for (int base = gb; base < ge; base += kChunk) {
    const int n  = min(kChunk, ge - base);    // uniform
    const int n4 = (n + 3) & ~3;              // padded group count
    __syncthreads();
    for (int i = tid; i < n4 + 16; i += 256) {
      const int idx = min(base + i, ge - 1);
      s_on[i] = ONS[idx];                               // valid address always
      s_fc[i] = (base + i < ge) ? FC[idx]
                                : make_float2(1.0f, 0.0f);  // pad: c=0 kills it
    }
    __syncthreads();

    const int4*   On4 = (const int4*)s_on;    // 4 grains per entry
    const float4* Fc4 = (const float4*)s_fc;  // 2 grains per entry

    // prologue: u queue = table values for grains 0..3 (addresses from On4[0]);
    // onQ = onsets 4..7; fc cur = grains 0..3.
    const int4 on0 = On4[0];
    float2 u0a = TG2[p0 - on0.x], u0b = TG2[p0 + 1 - on0.x];
    float2 u1a = TG2[p0 - on0.y], u1b = TG2[p0 + 1 - on0.y];
    float2 u2a = TG2[p0 - on0.z], u2b = TG2[p0 + 1 - on0.z];
    float2 u3a = TG2[p0 - on0.w], u3b = TG2[p0 + 1 - on0.w];
    int4   onQ = On4[1];
    float4 fcA = Fc4[0], fcB = Fc4[1];

    for (int t = 0; t < n4; t += 4) {
      // group-top reads (consumed next group: distance 4..7 iters)
      const int4   onI = On4[(t >> 2) + 2];          // onsets t+8..t+11
      const float4 fcI = Fc4[((t >> 2) + 1) * 2];    // fc t+4..t+5
      const float4 fcJ = Fc4[((t >> 2) + 1) * 2 + 1];// fc t+6..t+7

#pragma unroll
      for (int k = 0; k < 4; ++k) {
        // issue table loads for grain t+k+4 (per-lane VGPR address)
        const int onn = (k == 0) ? onQ.x : (k == 1) ? onQ.y
                       : (k == 2) ? onQ.z : onQ.w;
        const float2 na = TG2[p0 - onn];
        const float2 nb = TG2[p0 + 1 - onn];

        // compute grain t+k (u values loaded 4 iters ago)
        const float f0v = (k == 0) ? fcA.x : (k == 1) ? fcA.z
                         : (k == 2) ? fcB.x : fcB.z;
        const float cv  = (k == 0) ? fcA.y : (k == 1) ? fcA.w
                         : (k == 2) ? fcB.y : fcB.w;
        acc0 = fmaf(cv * u0a.y,
                    __builtin_amdgcn_sinf(__builtin_amdgcn_fractf(f0v * u0a.x)), acc0);
        acc1 = fmaf(cv * u0b.y,
                    __builtin_amdgcn_sinf(__builtin_amdgcn_fractf(f0v * u0b.x)), acc1);

        // rotate u queue (period 4 == unroll -> pure renaming)
        u0a = u1a; u0b = u1b; u1a = u2a; u1b = u2b;
        u2a = u3a; u2b = u3b; u3a = na;  u3b = nb;
      }
      onQ = onI; fcA = fcI; fcB = fcJ;
    }
  }

  // adjacent-sample float2 store (8B aligned: p0 even)
  *reinterpret_cast<float2*>(dst + p0) = make_float2(acc0, acc1);
}

// Combine halves (if COMBINE) and compute per-block sum of squares (f64).
template <bool COMBINE>
__global__ __launch_bounds__(256) void k_norm(float4* __restrict__ outA,
                                              const float4* __restrict__ outB,
                                              double* __restrict__ partials) {
  __shared__ double wpart[4];
  const int tid = threadIdx.x;
  const int i   = blockIdx.x * 256 + tid;
  float4 v = outA[i];
  if (COMBINE) {
    const float4 w = outB[i];
    v.x += w.x; v.y += w.y; v.z += w.z; v.w += w.w;
    outA[i] = v;
  }
  double p2 = (double)v.x * v.x + (double)v.y * v.y +
              (double)v.z * v.z + (double)v.w * v.w;
  for (int o = 32; o > 0; o >>= 1) p2 += __shfl_down(p2, o);
  if ((tid & 63) == 0) wpart[tid >> 6] = p2;
  __syncthreads();
  if (tid == 0) partials[blockIdx.x] = wpart[0] + wpart[1] + wpart[2] + wpart[3];
}

// Every block reduces the same 512 partials in the same order (deterministic,
// identical result), then scales its 1024-sample chunk by 1/sqrt(sum).
__global__ __launch_bounds__(256) void k_scale(const double* __restrict__ partials,
                                               float4* __restrict__ out) {
  __shared__ double red[256];
  const int tid = threadIdx.x;
  red[tid] = partials[tid] + partials[tid + 256];
  __syncthreads();
  for (int st = 128; st > 0; st >>= 1) {
    if (tid < st) red[tid] += red[tid + st];
    __syncthreads();
  }
  const float sc = (float)(1.0 / sqrt(red[0]));
  const int i = blockIdx.x * 256 + tid;
  float4 v = out[i];
  v.x *= sc; v.y *= sc; v.z *= sc; v.w *= sc;
  out[i] = v;
}

extern "C" void kernel_launch(void* const* d_in, const int* in_sizes, int n_in,
                              void* d_out, int out_size, void* d_ws, size_t ws_size,
                              hipStream_t stream) {
  const float* dens   = (const float*)d_in[0];
  const float* slope  = (const float*)d_in[1];
  const float* f0     = (const float*)d_in[2];
  const int*   onsets = (const int*)d_in[3];
  float* out = (float*)d_out;
  char*  ws  = (char*)d_ws;

  const int*    ONS  = (const int*)(ws + ONS_OFF);
  const float2* FC   = (const float2*)(ws + FC_OFF);
  const float2* TAB2 = (const float2*)(ws + TAB_OFF);
  double*       PART = (double*)(ws + PART_OFF);
  float*        out2 = (float*)(ws + OUT2_OFF);

  hipLaunchKernelGGL(k_setup, dim3(kSortBlocks + kTabN / 256), dim3(256), 0, stream,
                     dens, slope, f0, onsets, d_ws);

  if (ws_size >= kWsNeedSplit) {
    hipLaunchKernelGGL(k_main<2>, dim3(kNTiles * 2), dim3(256), 0, stream,
                       ONS, FC, TAB2, out, out2);
    hipLaunchKernelGGL(k_norm<true>, dim3(kNSamples / 1024), dim3(256), 0, stream,
                       (float4*)out, (const float4*)out2, PART);
  } else {
    hipLaunchKernelGGL(k_main<1>, dim3(kNTiles), dim3(256), 0, stream,
                       ONS, FC, TAB2, out, out2);
    hipLaunchKernelGGL(k_norm<false>, dim3(kNSamples / 1024), dim3(256), 0, stream,
                       (float4*)out, (const float4*)nullptr, PART);
  }
  hipLaunchKernelGGL(k_scale, dim3(kNSamples / 1024), dim3(256), 0, stream,
                     PART, (float4*)out);
}